// Round 3
// baseline (146.825 us; speedup 1.0000x reference)
//
#include <hip/hip_runtime.h>
#include <hip/hip_bf16.h>
#include <stdint.h>

// Problem constants (CompressedKVAttention_11708080848911)
#define Bc    4
#define Hc    32
#define HKVc  8
#define QLc   16
#define KVc   8192
#define Dc    128
#define NREPc 4   // H / HKV

typedef short bf16x8 __attribute__((ext_vector_type(8)));
typedef float f32x4  __attribute__((ext_vector_type(4)));
typedef int   i32x4  __attribute__((ext_vector_type(4)));

__device__ __forceinline__ unsigned short bf16_rne(float f) {
  union { float f; uint32_t u; } c{f};
  uint32_t u = c.u + 0x7FFFu + ((c.u >> 16) & 1u);
  return (unsigned short)(u >> 16);
}
// exact for integer-valued floats in [0,255] (low 16 mantissa bits are zero)
__device__ __forceinline__ short bf16_exact(float f) {
  union { float f; uint32_t u; } c{f};
  return (short)(unsigned short)(c.u >> 16);
}

// ---------------------------------------------------------------------------
// Phase 1: per-(b,g,split) flash partials.
// R2 fix: KV caches arrive as INT32 (harness promotes all integer inputs to
// int32: "integer -> const int*"). Previously read as int8 -> garbage K/V.
// Each token's 128 dims = 512 contiguous bytes now.
//
// Block = 256 threads = 4 waves; wave w handles query head g*4+w (16 rows).
// K: global -> register B-frags (u = k+128, exact in bf16), QK via MFMA.
// V: staged per 32 tokens into LDS transposed [d][t] bf16 (v+128), token bits
//    3..4 XOR-swizzled by (d>>4)&3 to break write bank conflicts.
// Scores: s_t*(dot_u - (z_t+128)*qsum_row), scale*log2e folded into s_t.
// Online-softmax max updated ONCE per 32-token block after both halves'
// scores are known (P in LDS always consistent with m used for acc/ell/corr).
// ---------------------------------------------------------------------------
__global__ __launch_bounds__(256) void attn_partial(
    const float* __restrict__ q, const int* __restrict__ kc,
    const int* __restrict__ vc,
    const float* __restrict__ ksc, const float* __restrict__ kzr,
    const float* __restrict__ vsc, const float* __restrict__ vzr,
    float* __restrict__ ws_acc, float* __restrict__ ws_m,
    float* __restrict__ ws_l, int nsplit)
{
  __shared__ __align__(16) unsigned short Vlds[128][40]; // rows 80B (16B-aligned)
  __shared__ __align__(16) unsigned short Plds[4][16][40];

  const int bid   = blockIdx.x;
  const int split = bid % nsplit;
  const int bg    = bid / nsplit;          // 0..31  (= b*HKV + g)
  const int chunk = KVc / nsplit;
  const int t_begin = split * chunk;

  const int tid  = threadIdx.x;
  const int wave = tid >> 6;
  const int lane = tid & 63;
  const int l15  = lane & 15;
  const int lg   = lane >> 4;              // 0..3

  const int b = bg >> 3, g = bg & 7;
  const int h = (g << 2) + wave;           // this wave's query head

  // ---- Q fragments (bf16) + per-row sum of bf16-rounded Q ----
  bf16x8 qa[4];
  float qsum = 0.f;
  const float* qrow = q + ((size_t)((b * Hc + h) * QLc + l15)) * Dc;
#pragma unroll
  for (int ks = 0; ks < 4; ++ks) {
    const float* p = qrow + ks * 32 + (lg << 3);
    bf16x8 f;
#pragma unroll
    for (int j = 0; j < 8; ++j) {
      unsigned short hb = bf16_rne(p[j]);
      f[j] = (short)hb;
      union { uint32_t u; float ff; } w{(uint32_t)hb << 16};
      qsum += w.ff;                        // sum of post-rounding values
    }
    qa[ks] = f;
  }
  qsum += __shfl_xor(qsum, 16);
  qsum += __shfl_xor(qsum, 32);            // every lane: qsum of row (lane&15)
  float qsumc[4];                          // re-map to C-layout rows 4*lg+j
#pragma unroll
  for (int j = 0; j < 4; ++j) qsumc[j] = __shfl(qsum, (lg << 2) + j);

  const float QK_SCALE = 0.088388347648f * 1.44269504089f; // d^-1/2 * log2(e)

  float m[4], ell[4], corr[4];
  f32x4 acc[8];
#pragma unroll
  for (int j = 0; j < 4; ++j) { m[j] = -1e30f; ell[j] = 0.f; corr[j] = 0.f; }
#pragma unroll
  for (int dt = 0; dt < 8; ++dt) acc[dt] = (f32x4){0.f, 0.f, 0.f, 0.f};

  const int*   kb   = kc  + (size_t)bg * KVc * Dc;
  const int*   vb   = vc  + (size_t)bg * KVc * Dc;
  const float* kscb = ksc + (size_t)bg * KVc;
  const float* kzrb = kzr + (size_t)bg * KVc;
  const float* vscb = vsc + (size_t)bg * KVc;
  const float* vzrb = vzr + (size_t)bg * KVc;

  for (int t0 = t_begin; t0 < t_begin + chunk; t0 += 32) {
    __syncthreads();
    { // ---- stage V: 32 tokens x 128 d, (v+128) bf16, transposed+swizzled ----
      const int t  = tid >> 3;             // 0..31
      const int d0 = (tid & 7) << 4;       // 0,16,...,112
      const int* src = vb + (size_t)(t0 + t) * Dc + d0;
      i32x4 w0 = *(const i32x4*)(src);
      i32x4 w1 = *(const i32x4*)(src + 4);
      i32x4 w2 = *(const i32x4*)(src + 8);
      i32x4 w3 = *(const i32x4*)(src + 12);
      const int tsw = t ^ (((d0 >> 4) & 3) << 3);  // XOR token bits 3..4
#pragma unroll
      for (int i = 0; i < 4; ++i) {
        Vlds[d0 + 0  + i][tsw] = (unsigned short)bf16_exact((float)(w0[i] + 128));
        Vlds[d0 + 4  + i][tsw] = (unsigned short)bf16_exact((float)(w1[i] + 128));
        Vlds[d0 + 8  + i][tsw] = (unsigned short)bf16_exact((float)(w2[i] + 128));
        Vlds[d0 + 12 + i][tsw] = (unsigned short)bf16_exact((float)(w3[i] + 128));
      }
    }
    __syncthreads();

    // ---- scores for BOTH halves (deferred max) ----
    float s8[2][4];
    float vsh[2], vzph[2];
#pragma unroll
    for (int half = 0; half < 2; ++half) {
      const int t = t0 + (half << 4) + l15;      // this lane's token (col)
      f32x4 sc = (f32x4){0.f, 0.f, 0.f, 0.f};
#pragma unroll
      for (int ks = 0; ks < 4; ++ks) {
        const int* kp = kb + (size_t)t * Dc + ks * 32 + (lg << 3);
        i32x4 a0 = *(const i32x4*)(kp);
        i32x4 a1 = *(const i32x4*)(kp + 4);
        bf16x8 kf;
#pragma unroll
        for (int j = 0; j < 4; ++j) {
          kf[j]     = bf16_exact((float)(a0[j] + 128));
          kf[4 + j] = bf16_exact((float)(a1[j] + 128));
        }
        sc = __builtin_amdgcn_mfma_f32_16x16x32_bf16(qa[ks], kf, sc, 0, 0, 0);
      }
      const float kscl = kscb[t] * QK_SCALE;
      const float kzp  = kzrb[t] + 128.f;
      vsh[half]  = vscb[t];
      vzph[half] = vzrb[t] + 128.f;
#pragma unroll
      for (int j = 0; j < 4; ++j)
        s8[half][j] = kscl * (sc[j] - kzp * qsumc[j]);
    }

    // ---- one max update + rescale per 32-token block ----
    float tm[4];
#pragma unroll
    for (int j = 0; j < 4; ++j) {
      tm[j] = fmaxf(s8[0][j], s8[1][j]);
      tm[j] = fmaxf(tm[j], __shfl_xor(tm[j], 1));
      tm[j] = fmaxf(tm[j], __shfl_xor(tm[j], 2));
      tm[j] = fmaxf(tm[j], __shfl_xor(tm[j], 4));
      tm[j] = fmaxf(tm[j], __shfl_xor(tm[j], 8));
    }
    bool need = false;
    float cf[4];
#pragma unroll
    for (int j = 0; j < 4; ++j) {
      float nm = fmaxf(m[j], tm[j]);
      cf[j] = exp2f(m[j] - nm);
      need = need || (tm[j] > m[j]);
      m[j] = nm;
    }
    if (__any(need)) {                     // wave-uniform rescale (rare later)
#pragma unroll
      for (int j = 0; j < 4; ++j) { ell[j] *= cf[j]; corr[j] *= cf[j]; }
#pragma unroll
      for (int dt = 0; dt < 8; ++dt)
#pragma unroll
        for (int j = 0; j < 4; ++j) acc[dt][j] *= cf[j];
    }

    // ---- P (consistent with final m) + fold value_scale; write Plds ----
#pragma unroll
    for (int half = 0; half < 2; ++half) {
#pragma unroll
      for (int j = 0; j < 4; ++j) {
        float p = exp2f(s8[half][j] - m[j]);
        ell[j] += p;
        unsigned short pb = bf16_rne(p * vsh[half]);
        union { uint32_t u; float ff; } pw{(uint32_t)pb << 16};
        corr[j] += pw.ff * vzph[half];     // use ROUNDED P' for consistency
        Plds[wave][(lg << 2) + j][(half << 4) + l15] = pb;
      }
    }

    // ---- PV for these 32 tokens ----
    bf16x8 pa = *(const bf16x8*)&Plds[wave][l15][lg << 3];
#pragma unroll
    for (int dt = 0; dt < 8; ++dt) {
      bf16x8 vbf = *(const bf16x8*)&Vlds[(dt << 4) + l15][(lg ^ (dt & 3)) << 3];
      acc[dt] = __builtin_amdgcn_mfma_f32_16x16x32_bf16(pa, vbf, acc[dt], 0, 0, 0);
    }
  }

  // ---- final lane reductions over token slots ----
#pragma unroll
  for (int j = 0; j < 4; ++j) {
    ell[j] += __shfl_xor(ell[j], 1);  ell[j] += __shfl_xor(ell[j], 2);
    ell[j] += __shfl_xor(ell[j], 4);  ell[j] += __shfl_xor(ell[j], 8);
    corr[j] += __shfl_xor(corr[j], 1); corr[j] += __shfl_xor(corr[j], 2);
    corr[j] += __shfl_xor(corr[j], 4); corr[j] += __shfl_xor(corr[j], 8);
  }

  const size_t pbase = ((size_t)bg * nsplit + split) * 64;
#pragma unroll
  for (int dt = 0; dt < 8; ++dt)
#pragma unroll
    for (int j = 0; j < 4; ++j) {
      int row = (wave << 4) + (lg << 2) + j;
      int d   = (dt << 4) + l15;
      ws_acc[(pbase + row) * Dc + d] = acc[dt][j] - corr[j];
    }
  if (l15 == 0) {
#pragma unroll
    for (int j = 0; j < 4; ++j) {
      int row = (wave << 4) + (lg << 2) + j;
      ws_m[pbase + row] = m[j];
      ws_l[pbase + row] = ell[j];
    }
  }
}

// ---------------------------------------------------------------------------
// Phase 2: flash-combine partials and normalize. One block per (bg,row).
// ---------------------------------------------------------------------------
__global__ __launch_bounds__(128) void attn_combine(
    const float* __restrict__ ws_acc, const float* __restrict__ ws_m,
    const float* __restrict__ ws_l, float* __restrict__ out, int nsplit)
{
  const int r   = blockIdx.x;      // 0 .. 32*64-1
  const int bg  = r >> 6;
  const int row = r & 63;
  const int d   = threadIdx.x;     // 0..127

  float M = -1e30f;
  for (int i = 0; i < nsplit; ++i)
    M = fmaxf(M, ws_m[((size_t)bg * nsplit + i) * 64 + row]);
  float L = 0.f, o = 0.f;
  for (int i = 0; i < nsplit; ++i) {
    size_t pb = ((size_t)bg * nsplit + i) * 64 + row;
    float w = exp2f(ws_m[pb] - M);
    L += ws_l[pb] * w;
    o += ws_acc[pb * Dc + d] * w;
  }
  const int b = bg >> 3, g = bg & 7;
  const int rep = row >> 4, qq = row & 15;
  out[(((size_t)(b * Hc + g * NREPc + rep)) * QLc + qq) * Dc + d] = o / L;
}

extern "C" void kernel_launch(void* const* d_in, const int* in_sizes, int n_in,
                              void* d_out, int out_size, void* d_ws,
                              size_t ws_size, hipStream_t stream) {
  const float* q   = (const float*)d_in[0];
  const int*   kc  = (const int*)d_in[1];   // int8 values promoted to int32
  const int*   vc  = (const int*)d_in[2];   // by the harness ("integer -> int*")
  const float* ksc = (const float*)d_in[3];
  const float* kzr = (const float*)d_in[4];
  const float* vsc = (const float*)d_in[5];
  const float* vzr = (const float*)d_in[6];
  float* out = (float*)d_out;

  int nsplit = 16;                         // 512 blocks; fallback if ws small
  while (nsplit > 1) {
    size_t need = (size_t)32 * nsplit * 64 * (Dc + 2) * sizeof(float);
    if (need <= ws_size) break;
    nsplit >>= 1;
  }
  float* ws_acc = (float*)d_ws;                             // [32,ns,64,128]
  float* ws_m   = ws_acc + (size_t)32 * nsplit * 64 * Dc;   // [32,ns,64]
  float* ws_l   = ws_m   + (size_t)32 * nsplit * 64;        // [32,ns,64]

  attn_partial<<<dim3(32 * nsplit), dim3(256), 0, stream>>>(
      q, kc, vc, ksc, kzr, vsc, vzr, ws_acc, ws_m, ws_l, nsplit);
  attn_combine<<<dim3(32 * 64), dim3(128), 0, stream>>>(
      ws_acc, ws_m, ws_l, out, nsplit);
}